// Round 12
// baseline (436.030 us; speedup 1.0000x reference)
//
#include <hip/hip_runtime.h>
#include <math.h>

typedef _Float16 f16;
typedef _Float16 f16x8 __attribute__((ext_vector_type(8)));
typedef _Float16 f16x4 __attribute__((ext_vector_type(4)));
typedef float f32x4 __attribute__((ext_vector_type(4)));

#define N_NODES 50000
#define N_EDGES 800000
#define HID 64
#define HEADS 8
#define DH 8
#define LAYERS 6
#define EDGE_DIM 16
#define SIGN_DIM 8
#define NSIGN 3
#define VOC 512
#define NCOMB (VOC * NSIGN)
#define EPS 1e-5f

// coarse-bucket sort params
#define NBUCK 196
#define BUCK_CAP 5120
#define BIN_EPB 4096
#define BIN_EPT 16
#define BIN_NBLK ((N_EDGES + BIN_EPB - 1) / BIN_EPB)

// prep kernel grid ranges
#define WP_BLK 384
#define TE_BLK (LAYERS * (NCOMB / 16))
#define PREP_BLK (WP_BLK + TE_BLK + 1)

__device__ __forceinline__ float dot8(f16x8 a, f16x8 b, float c) {
#if __has_builtin(__builtin_amdgcn_fdot2)
    c = __builtin_amdgcn_fdot2(__builtin_shufflevector(a, a, 0, 1),
                               __builtin_shufflevector(b, b, 0, 1), c, false);
    c = __builtin_amdgcn_fdot2(__builtin_shufflevector(a, a, 2, 3),
                               __builtin_shufflevector(b, b, 2, 3), c, false);
    c = __builtin_amdgcn_fdot2(__builtin_shufflevector(a, a, 4, 5),
                               __builtin_shufflevector(b, b, 4, 5), c, false);
    c = __builtin_amdgcn_fdot2(__builtin_shufflevector(a, a, 6, 7),
                               __builtin_shufflevector(b, b, 6, 7), c, false);
#else
#pragma unroll
    for (int i = 0; i < 8; ++i) c += (float)a[i] * (float)b[i];
#endif
    return c;
}

// ---------------- prep: weight prep + TE table + inits
__global__ __launch_bounds__(256) void k_prep(
    const float* __restrict__ Wq, const float* __restrict__ bq,
    const float* __restrict__ Wk, const float* __restrict__ bk,
    const float* __restrict__ Wv, const float* __restrict__ bv,
    const float* __restrict__ Ws, const float* __restrict__ bs,
    f16* __restrict__ wcatT, float* __restrict__ bcat,
    const float* __restrict__ emb_s, const float* __restrict__ emb_sg,
    const float* __restrict__ We, const float* __restrict__ be,
    const float* __restrict__ Wedge, f16* __restrict__ TE,
    int* __restrict__ bcur, int* __restrict__ rowptr,
    float* __restrict__ gsumR) {
    int b = blockIdx.x;
    int t = threadIdx.x;
    if (b < WP_BLK) {
        int idx = b * 256 + t;
        int l = idx >> 14;
        int r = idx & 16383;
        int c = r >> 6, kk = r & 63;
        int m = c >> 6, cc = c & 63;
        const float* W = (m == 0) ? Wq : (m == 1) ? Wk : (m == 2) ? Wv : Ws;
        wcatT[idx] = (f16)W[l * 4096 + kk * 64 + cc];
        if (kk == 0) {
            const float* B = (m == 0) ? bq : (m == 1) ? bk : (m == 2) ? bv : bs;
            bcat[l * 256 + c] = B[l * 64 + cc];
        }
        return;
    }
    b -= WP_BLK;
    if (b < TE_BLK) {
        __shared__ float T[16][16];
        int l = b / (NCOMB / 16);
        int comb0 = (b % (NCOMB / 16)) * 16;
        int cl = t >> 4, c = t & 15;
        int comb = comb0 + cl;
        int lb = comb / NSIGN, sg = comb % NSIGN;
        float acc = be[c];
        const float* er = emb_s + lb * HID;
#pragma unroll
        for (int j = 0; j < HID; ++j) acc += er[j] * We[j * EDGE_DIM + c];
        const float* sr = emb_sg + sg * SIGN_DIM;
#pragma unroll
        for (int j = 0; j < SIGN_DIM; ++j) acc += sr[j] * We[(HID + j) * EDGE_DIM + c];
        T[cl][c] = acc;
        __syncthreads();
        const float* w = Wedge + l * EDGE_DIM * HID;
#pragma unroll
        for (int rep = 0; rep < 4; ++rep) {
            int idx = rep * 256 + t;
            int cml = idx >> 6, d = idx & 63;
            float a = 0.f;
#pragma unroll
            for (int j = 0; j < EDGE_DIM; ++j) a += T[cml][j] * w[j * HID + d];
            TE[((size_t)l * NCOMB + comb0 + cml) * HID + d] = (f16)a;
        }
        return;
    }
    if (t < NBUCK) bcur[t] = 0;
    for (int i = t; i < 512; i += 256) gsumR[i] = 0.f;
    if (t == 0) rowptr[N_NODES] = N_EDGES;
}

// ---------------- store helper: lane owns 4 consecutive channels of node nn
__device__ __forceinline__ void proj_store(
    f16* __restrict__ q, f16* __restrict__ kv, f16* __restrict__ sk,
    int nn, int cbase, f32x4 z, const float* __restrict__ bcat_l) {
    f16x4 val;
#pragma unroll
    for (int r = 0; r < 4; ++r) val[r] = (f16)(z[r] + bcat_l[cbase + r]);
    int m = cbase >> 6, cc = cbase & 63;
    f16* dst = (m == 0) ? (q + (nn << 6) + cc)
             : (m == 1) ? (kv + (size_t)nn * 128 + cc)
             : (m == 2) ? (kv + (size_t)nn * 128 + 64 + cc)
                        : (sk + (nn << 6) + cc);
    *(f16x4*)dst = val;
}

// ---------------- node features + layer-0 projection (16 nodes/block, A=W B=x)
__global__ __launch_bounds__(256) void k_nfproj(
    const int* __restrict__ xn, const float* __restrict__ emb_s,
    const float* __restrict__ emb_p, const f16* __restrict__ wcatT0,
    const float* __restrict__ bcat0,
    f16* __restrict__ q, f16* __restrict__ kv, f16* __restrict__ sk) {
    __shared__ __align__(16) f16 xs[16][72];
    int t = threadIdx.x;
    int n0 = blockIdx.x * 16;
#pragma unroll
    for (int i = 0; i < 4; ++i) {
        int idx = i * 256 + t;
        int row = idx >> 6, col = idx & 63;
        int n = n0 + row;
        float acc = 0.f;
#pragma unroll
        for (int s = 0; s < 4; ++s) {
            int id = xn[n * 4 + s];
            acc += emb_s[id * HID + col] + emb_p[s * HID + col];
        }
        xs[row][col] = (f16)acc;
    }
    __syncthreads();
    int w = t >> 6, l = t & 63;
    int kb = l >> 4;
    int nn = n0 + (l & 15);
    f16x8 b0 = *(const f16x8*)(&xs[l & 15][kb << 3]);
    f16x8 b1 = *(const f16x8*)(&xs[l & 15][32 + (kb << 3)]);
#pragma unroll
    for (int tt = 0; tt < 4; ++tt) {
        int ct = (w << 2) + tt;
        const f16* wr = wcatT0 + (((ct << 4) + (l & 15)) << 6) + (kb << 3);
        f16x8 a0 = *(const f16x8*)(wr);
        f16x8 a1 = *(const f16x8*)(wr + 32);
        f32x4 z = {0.f, 0.f, 0.f, 0.f};
        z = __builtin_amdgcn_mfma_f32_16x16x32_f16(a0, b0, z, 0, 0, 0);
        z = __builtin_amdgcn_mfma_f32_16x16x32_f16(a1, b1, z, 0, 0, 0);
        proj_store(q, kv, sk, nn, (ct << 4) + ((l >> 4) << 2), z, bcat0);
    }
}

// ---------------- phase 1: bin edges into coarse buckets
__global__ __launch_bounds__(256) void k_bin(
    const int* __restrict__ src, const int* __restrict__ dst,
    const int* __restrict__ label, const int* __restrict__ sign,
    int* __restrict__ bcur, int2* __restrict__ buf) {
    __shared__ int hist[NBUCK];
    __shared__ int base[NBUCK];
    int t = threadIdx.x;
    for (int i = t; i < NBUCK; i += 256) hist[i] = 0;
    __syncthreads();
    int e0 = blockIdx.x * BIN_EPB;
    int pk[BIN_EPT], dl[BIN_EPT], bl[BIN_EPT], loc[BIN_EPT];
#pragma unroll
    for (int i = 0; i < BIN_EPT; ++i) {
        int e = e0 + i * 256 + t;
        bool vld = e < N_EDGES;
        int d = vld ? dst[e] : 0;
        bl[i] = d >> 8;
        dl[i] = d & 255;
        pk[i] = vld ? ((src[e] << 11) | (label[e] * NSIGN + sign[e])) : 0;
        loc[i] = vld ? atomicAdd(&hist[bl[i]], 1) : -1;
    }
    __syncthreads();
    if (t < NBUCK) {
        int h = hist[t];
        int gb = h ? atomicAdd(&bcur[t], h) : 0;
        base[t] = t * BUCK_CAP + gb;
    }
    __syncthreads();
#pragma unroll
    for (int i = 0; i < BIN_EPT; ++i)
        if (loc[i] >= 0) buf[base[bl[i]] + loc[i]] = make_int2(pk[i], dl[i]);
}

// ---------------- phase 2: inline bucket scan + per-bucket rowptr + CSR scatter
__global__ __launch_bounds__(256) void k_place(
    const int* __restrict__ bcur, const int2* __restrict__ buf,
    int* __restrict__ rowptr, int* __restrict__ scomb) {
    __shared__ int hist[256];
    __shared__ int curs[256];
    __shared__ int wsA[4];
    __shared__ int wsB[4];
    __shared__ int sbase;
    int t = threadIdx.x, b = blockIdx.x;
    int lane = t & 63, w = t >> 6;
    int v = (t < NBUCK) ? bcur[t] : 0;
    int incl = v;
#pragma unroll
    for (int o = 1; o < 64; o <<= 1) {
        int u = __shfl_up(incl, o);
        if (lane >= o) incl += u;
    }
    if (lane == 63) wsA[w] = incl;
    hist[t] = 0;
    __syncthreads();
    int woff = 0;
    for (int j = 0; j < w; ++j) woff += wsA[j];
    if (t == b) sbase = woff + incl - v;
    __syncthreads();
    int cnt = bcur[b];
    const int2* bb = buf + (size_t)b * BUCK_CAP;
    for (int i = t; i < cnt; i += 256) atomicAdd(&hist[bb[i].y], 1);
    __syncthreads();
    int hv = hist[t];
    int hincl = hv;
#pragma unroll
    for (int o = 1; o < 64; o <<= 1) {
        int u = __shfl_up(hincl, o);
        if (lane >= o) hincl += u;
    }
    if (lane == 63) wsB[w] = hincl;
    __syncthreads();
    int hoff = 0;
    for (int j = 0; j < w; ++j) hoff += wsB[j];
    int start = sbase + hoff + hincl - hv;
    int n = (b << 8) + t;
    if (n < N_NODES) rowptr[n] = start;
    curs[t] = start;
    __syncthreads();
    for (int i = t; i < cnt; i += 256) {
        int2 r = bb[i];
        int pos = atomicAdd(&curs[r.y], 1);
        scomb[pos] = r.x;
    }
}

// ---------------- MFMA projection (layers 1..5), A=W B=x, coalesced 8B stores
__global__ __launch_bounds__(256) void k_proj(
    const f16* __restrict__ x16, const f16* __restrict__ wcatT_l,
    const float* __restrict__ bcat_l,
    f16* __restrict__ q, f16* __restrict__ kv, f16* __restrict__ sk) {
    int t = threadIdx.x;
    int w = t >> 6, l = t & 63;
    int n0 = blockIdx.x * 16;
    int kb = l >> 4;
    int nn = n0 + (l & 15);
    const f16* xr = x16 + (nn << 6) + (kb << 3);
    f16x8 b0 = *(const f16x8*)(xr);
    f16x8 b1 = *(const f16x8*)(xr + 32);
#pragma unroll
    for (int tt = 0; tt < 4; ++tt) {
        int ct = (w << 2) + tt;
        const f16* wr = wcatT_l + (((ct << 4) + (l & 15)) << 6) + (kb << 3);
        f16x8 a0 = *(const f16x8*)(wr);
        f16x8 a1 = *(const f16x8*)(wr + 32);
        f32x4 z = {0.f, 0.f, 0.f, 0.f};
        z = __builtin_amdgcn_mfma_f32_16x16x32_f16(a0, b0, z, 0, 0, 0);
        z = __builtin_amdgcn_mfma_f32_16x16x32_f16(a1, b1, z, 0, 0, 0);
        proj_store(q, kv, sk, nn, (ct << 4) + ((l >> 4) << 2), z, bcat_l);
    }
}

// ---------------- 2-node-per-wave aggregation core (doubles gather MLP)
#define AGG2_BODY()                                                              \
    int e = lane >> 3;                                                           \
    int h = lane & 7;                                                            \
    int d = (h << 3) + e;                                                        \
    int nA = nbase, nB = nbase + 1;                                              \
    float skvA = (float)sk[(nA << 6) + d];                                       \
    float skvB = (float)sk[(nB << 6) + d];                                       \
    f16x8 qfA = *(const f16x8*)(q + (nA << 6) + (h << 3));                       \
    f16x8 qfB = *(const f16x8*)(q + (nB << 6) + (h << 3));                       \
    int rsA = rowptr[nA], reA = rowptr[nA + 1];                                  \
    int rsB = rowptr[nB], reB = rowptr[nB + 1];                                  \
    const float scale = 0.35355339059327373f;                                    \
    float lsA = 0.f, lsB = 0.f;                                                  \
    float aA0 = 0.f, aA1 = 0.f, aA2 = 0.f, aA3 = 0.f;                            \
    float aA4 = 0.f, aA5 = 0.f, aA6 = 0.f, aA7 = 0.f;                            \
    float aB0 = 0.f, aB1 = 0.f, aB2 = 0.f, aB3 = 0.f;                            \
    float aB4 = 0.f, aB5 = 0.f, aB6 = 0.f, aB7 = 0.f;                            \
    for (int jA = rsA, jB = rsB; jA < reA || jB < reB; jA += 16, jB += 16) {     \
        int ja1 = jA + e, ja2 = jA + 8 + e;                                      \
        int jb1 = jB + e, jb2 = jB + 8 + e;                                      \
        bool vA1 = ja1 < reA, vA2 = ja2 < reA;                                   \
        bool vB1 = jb1 < reB, vB2 = jb2 < reB;                                   \
        int pA1 = scomb[vA1 ? ja1 : rsA];                                        \
        int pA2 = scomb[vA2 ? ja2 : rsA];                                        \
        int pB1 = scomb[vB1 ? jb1 : rsB];                                        \
        int pB2 = scomb[vB2 ? jb2 : rsB];                                        \
        const f16* cA1 = kv + ((size_t)(pA1 >> 11) << 7) + (h << 3);             \
        const f16* cA2 = kv + ((size_t)(pA2 >> 11) << 7) + (h << 3);             \
        const f16* cB1 = kv + ((size_t)(pB1 >> 11) << 7) + (h << 3);             \
        const f16* cB2 = kv + ((size_t)(pB2 >> 11) << 7) + (h << 3);             \
        f16x8 kA1 = *(const f16x8*)(cA1);                                        \
        f16x8 vA1f = *(const f16x8*)(cA1 + 64);                                  \
        f16x8 tA1 = *(const f16x8*)(te + ((pA1 & 2047) << 6) + (h << 3));        \
        f16x8 kA2 = *(const f16x8*)(cA2);                                        \
        f16x8 vA2f = *(const f16x8*)(cA2 + 64);                                  \
        f16x8 tA2 = *(const f16x8*)(te + ((pA2 & 2047) << 6) + (h << 3));        \
        f16x8 kB1 = *(const f16x8*)(cB1);                                        \
        f16x8 vB1f = *(const f16x8*)(cB1 + 64);                                  \
        f16x8 tB1 = *(const f16x8*)(te + ((pB1 & 2047) << 6) + (h << 3));        \
        f16x8 kB2 = *(const f16x8*)(cB2);                                        \
        f16x8 vB2f = *(const f16x8*)(cB2 + 64);                                  \
        f16x8 tB2 = *(const f16x8*)(te + ((pB2 & 2047) << 6) + (h << 3));        \
        float alA1 = dot8(qfA, kA1 + tA1, 0.f) * scale;                          \
        float alA2 = dot8(qfA, kA2 + tA2, 0.f) * scale;                          \
        float alB1 = dot8(qfB, kB1 + tB1, 0.f) * scale;                          \
        float alB2 = dot8(qfB, kB2 + tB2, 0.f) * scale;                          \
        float wA1 = vA1 ? __expf(alA1) : 0.f;                                    \
        float wA2 = vA2 ? __expf(alA2) : 0.f;                                    \
        float wB1 = vB1 ? __expf(alB1) : 0.f;                                    \
        float wB2 = vB2 ? __expf(alB2) : 0.f;                                    \
        lsA += wA1 + wA2;                                                        \
        lsB += wB1 + wB2;                                                        \
        f16x8 uA1 = vA1f + tA1;                                                  \
        f16x8 uA2 = vA2f + tA2;                                                  \
        f16x8 uB1 = vB1f + tB1;                                                  \
        f16x8 uB2 = vB2f + tB2;                                                  \
        aA0 += wA1 * (float)uA1[0] + wA2 * (float)uA2[0];                        \
        aA1 += wA1 * (float)uA1[1] + wA2 * (float)uA2[1];                        \
        aA2 += wA1 * (float)uA1[2] + wA2 * (float)uA2[2];                        \
        aA3 += wA1 * (float)uA1[3] + wA2 * (float)uA2[3];                        \
        aA4 += wA1 * (float)uA1[4] + wA2 * (float)uA2[4];                        \
        aA5 += wA1 * (float)uA1[5] + wA2 * (float)uA2[5];                        \
        aA6 += wA1 * (float)uA1[6] + wA2 * (float)uA2[6];                        \
        aA7 += wA1 * (float)uA1[7] + wA2 * (float)uA2[7];                        \
        aB0 += wB1 * (float)uB1[0] + wB2 * (float)uB2[0];                        \
        aB1 += wB1 * (float)uB1[1] + wB2 * (float)uB2[1];                        \
        aB2 += wB1 * (float)uB1[2] + wB2 * (float)uB2[2];                        \
        aB3 += wB1 * (float)uB1[3] + wB2 * (float)uB2[3];                        \
        aB4 += wB1 * (float)uB1[4] + wB2 * (float)uB2[4];                        \
        aB5 += wB1 * (float)uB1[5] + wB2 * (float)uB2[5];                        \
        aB6 += wB1 * (float)uB1[6] + wB2 * (float)uB2[6];                        \
        aB7 += wB1 * (float)uB1[7] + wB2 * (float)uB2[7];                        \
    }                                                                            \
    _Pragma("unroll")                                                            \
    for (int o = 8; o < 64; o <<= 1) {                                           \
        lsA += __shfl_xor(lsA, o);                                               \
        aA0 += __shfl_xor(aA0, o);                                               \
        aA1 += __shfl_xor(aA1, o);                                               \
        aA2 += __shfl_xor(aA2, o);                                               \
        aA3 += __shfl_xor(aA3, o);                                               \
        aA4 += __shfl_xor(aA4, o);                                               \
        aA5 += __shfl_xor(aA5, o);                                               \
        aA6 += __shfl_xor(aA6, o);                                               \
        aA7 += __shfl_xor(aA7, o);                                               \
        lsB += __shfl_xor(lsB, o);                                               \
        aB0 += __shfl_xor(aB0, o);                                               \
        aB1 += __shfl_xor(aB1, o);                                               \
        aB2 += __shfl_xor(aB2, o);                                               \
        aB3 += __shfl_xor(aB3, o);                                               \
        aB4 += __shfl_xor(aB4, o);                                               \
        aB5 += __shfl_xor(aB5, o);                                               \
        aB6 += __shfl_xor(aB6, o);                                               \
        aB7 += __shfl_xor(aB7, o);                                               \
    }                                                                            \
    float avA = aA0, avB = aB0;                                                  \
    avA = (e == 1) ? aA1 : avA; avB = (e == 1) ? aB1 : avB;                      \
    avA = (e == 2) ? aA2 : avA; avB = (e == 2) ? aB2 : avB;                      \
    avA = (e == 3) ? aA3 : avA; avB = (e == 3) ? aB3 : avB;                      \
    avA = (e == 4) ? aA4 : avA; avB = (e == 4) ? aB4 : avB;                      \
    avA = (e == 5) ? aA5 : avA; avB = (e == 5) ? aB5 : avB;                      \
    avA = (e == 6) ? aA6 : avA; avB = (e == 6) ? aB6 : avB;                      \
    avA = (e == 7) ? aA7 : avA; avB = (e == 7) ? aB7 : avB;                      \
    float outvA = avA / (lsA + 1e-16f) + skvA;                                   \
    float outvB = avB / (lsB + 1e-16f) + skvB;

// ---------------- aggregation + skip + LN/ReLU (layers 0..4), 2 nodes/wave
__global__ __launch_bounds__(256) void k_aggL(
    const f16* __restrict__ q, const f16* __restrict__ kv,
    const f16* __restrict__ sk, const f16* __restrict__ te,
    const int* __restrict__ scomb, const int* __restrict__ rowptr,
    const float* __restrict__ ln_g, const float* __restrict__ ln_b,
    f16* __restrict__ xout) {
    int t = threadIdx.x;
    int wid = t >> 6, lane = t & 63;
    int nbase = blockIdx.x * 8 + wid * 2;
    AGG2_BODY()
    float sA = outvA, sB = outvB;
#pragma unroll
    for (int o = 1; o < 64; o <<= 1) {
        sA += __shfl_xor(sA, o);
        sB += __shfl_xor(sB, o);
    }
    float muA = sA * (1.f / 64.f), muB = sB * (1.f / 64.f);
    float dvA = outvA - muA, dvB = outvB - muB;
    float vsA = dvA * dvA, vsB = dvB * dvB;
#pragma unroll
    for (int o = 1; o < 64; o <<= 1) {
        vsA += __shfl_xor(vsA, o);
        vsB += __shfl_xor(vsB, o);
    }
    float g = ln_g[d], bb = ln_b[d];
    float yA = g * dvA / sqrtf(vsA * (1.f / 64.f) + EPS) + bb;
    float yB = g * dvB / sqrtf(vsB * (1.f / 64.f) + EPS) + bb;
    xout[(nA << 6) + d] = (f16)fmaxf(yA, 0.f);
    xout[(nB << 6) + d] = (f16)fmaxf(yB, 0.f);
}

// ---------------- final-layer aggregation + policy + fused colsum, 2 nodes/wave
__global__ __launch_bounds__(256) void k_aggF(
    const f16* __restrict__ q, const f16* __restrict__ kv,
    const f16* __restrict__ sk, const f16* __restrict__ te,
    const int* __restrict__ scomb, const int* __restrict__ rowptr,
    const float* __restrict__ Wp, const float* __restrict__ bp,
    float* __restrict__ pol, float* __restrict__ gsumR) {
    __shared__ float sh[8][64];
    int t = threadIdx.x;
    int wid = t >> 6, lane = t & 63;
    int nbase = blockIdx.x * 8 + wid * 2;
    AGG2_BODY()
    float w0 = Wp[d * 2 + 0], w1 = Wp[d * 2 + 1];
    float pA0 = outvA * w0, pA1 = outvA * w1;
    float pB0 = outvB * w0, pB1 = outvB * w1;
#pragma unroll
    for (int o = 1; o < 64; o <<= 1) {
        pA0 += __shfl_xor(pA0, o);
        pA1 += __shfl_xor(pA1, o);
        pB0 += __shfl_xor(pB0, o);
        pB1 += __shfl_xor(pB1, o);
    }
    if (lane == 0) {
        pol[nA * 2 + 0] = pA0 + bp[0];
        pol[nA * 2 + 1] = pA1 + bp[1];
        pol[nB * 2 + 0] = pB0 + bp[0];
        pol[nB * 2 + 1] = pB1 + bp[1];
    }
    sh[wid * 2][d] = outvA;
    sh[wid * 2 + 1][d] = outvB;
    __syncthreads();
    if (wid == 0) {
        float s = 0.f;
#pragma unroll
        for (int r = 0; r < 8; ++r) s += sh[r][lane];
        atomicAdd(&gsumR[((blockIdx.x & 7) << 6) + lane], s);
    }
}

// ---------------- value head
__global__ __launch_bounds__(64) void k_value(
    const float* __restrict__ gsumR, const float* __restrict__ Wv1,
    const float* __restrict__ bv1, const float* __restrict__ Wv2,
    const float* __restrict__ bv2, float* __restrict__ out) {
    int lane = threadIdx.x;
    __shared__ float g[64];
    float gs = 0.f;
#pragma unroll
    for (int r = 0; r < 8; ++r) gs += gsumR[(r << 6) + lane];
    g[lane] = gs * (1.f / N_NODES);
    __syncthreads();
    float h = bv1[lane];
    for (int i = 0; i < HID; ++i) h += g[i] * Wv1[i * HID + lane];
    h = fmaxf(h, 0.f);
    float p = h * Wv2[lane];
#pragma unroll
    for (int o = 1; o < 64; o <<= 1) p += __shfl_xor(p, o);
    if (lane == 0) out[0] = tanhf(p + bv2[0]);
}

extern "C" void kernel_launch(void* const* d_in, const int* in_sizes, int n_in,
                              void* d_out, int out_size, void* d_ws, size_t ws_size,
                              hipStream_t stream) {
    const int* x_nodes = (const int*)d_in[0];
    const int* edge_index = (const int*)d_in[1];
    const int* edge_label = (const int*)d_in[2];
    const int* edge_sign = (const int*)d_in[3];
    const float* emb_strand = (const float*)d_in[4];
    const float* emb_pos = (const float*)d_in[5];
    const float* emb_sign = (const float*)d_in[6];
    const float* We = (const float*)d_in[7];
    const float* be = (const float*)d_in[8];
    const float* Wq = (const float*)d_in[9];
    const float* bq = (const float*)d_in[10];
    const float* Wk = (const float*)d_in[11];
    const float* bk = (const float*)d_in[12];
    const float* Wv = (const float*)d_in[13];
    const float* bv = (const float*)d_in[14];
    const float* Wedge = (const float*)d_in[15];
    const float* Wskip = (const float*)d_in[16];
    const float* bskip = (const float*)d_in[17];
    const float* ln_g = (const float*)d_in[18];
    const float* ln_b = (const float*)d_in[19];
    const float* Wp = (const float*)d_in[20];
    const float* bp = (const float*)d_in[21];
    const float* Wv1 = (const float*)d_in[22];
    const float* bv1 = (const float*)d_in[23];
    const float* Wv2 = (const float*)d_in[24];
    const float* bv2 = (const float*)d_in[25];
    float* out = (float*)d_out;

    const int* src = edge_index;
    const int* dst = edge_index + N_EDGES;

    char* ws = (char*)d_ws;
    size_t off = 0;
    auto alloc = [&](size_t bytes) -> void* {
        void* p = ws + off;
        off += (bytes + 255) & ~(size_t)255;
        return p;
    };
    f16* x16 = (f16*)alloc((size_t)N_NODES * HID * 2);
    f16* q = (f16*)alloc((size_t)N_NODES * HID * 2);
    f16* kv = (f16*)alloc((size_t)N_NODES * 128 * 2);
    f16* sk = (f16*)alloc((size_t)N_NODES * HID * 2);
    int* scomb = (int*)alloc((size_t)N_EDGES * 4);
    int2* binbuf = (int2*)alloc((size_t)NBUCK * BUCK_CAP * 8);
    int* rowptr = (int*)alloc((size_t)(N_NODES + 1) * 4);
    int* bcur = (int*)alloc((size_t)NBUCK * 4);
    f16* TE = (f16*)alloc((size_t)LAYERS * NCOMB * HID * 2);
    f16* wcatT = (f16*)alloc((size_t)LAYERS * 256 * HID * 2);
    float* bcat = (float*)alloc((size_t)LAYERS * 256 * 4);
    float* gsumR = (float*)alloc(512 * 4);

    k_prep<<<PREP_BLK, 256, 0, stream>>>(
        Wq, bq, Wk, bk, Wv, bv, Wskip, bskip, wcatT, bcat,
        emb_strand, emb_sign, We, be, Wedge, TE, bcur, rowptr, gsumR);
    k_nfproj<<<N_NODES / 16, 256, 0, stream>>>(
        x_nodes, emb_strand, emb_pos, wcatT, bcat, q, kv, sk);
    k_bin<<<BIN_NBLK, 256, 0, stream>>>(src, dst, edge_label, edge_sign, bcur, binbuf);
    k_place<<<NBUCK, 256, 0, stream>>>(bcur, binbuf, rowptr, scomb);

    for (int l = 0; l < LAYERS - 1; ++l) {
        k_aggL<<<N_NODES / 8, 256, 0, stream>>>(
            q, kv, sk, TE + (size_t)l * NCOMB * HID, scomb, rowptr,
            ln_g + (size_t)l * HID, ln_b + (size_t)l * HID, x16);
        k_proj<<<N_NODES / 16, 256, 0, stream>>>(
            x16, wcatT + (size_t)(l + 1) * 256 * HID, bcat + (size_t)(l + 1) * 256,
            q, kv, sk);
    }
    k_aggF<<<N_NODES / 8, 256, 0, stream>>>(
        q, kv, sk, TE + (size_t)(LAYERS - 1) * NCOMB * HID, scomb, rowptr,
        Wp, bp, out, gsumR);
    k_value<<<1, 64, 0, stream>>>(gsumR, Wv1, bv1, Wv2, bv2, out + 2 * N_NODES);
}

// Round 13
// 388.572 us; speedup vs baseline: 1.1221x; 1.1221x over previous
//
#include <hip/hip_runtime.h>
#include <math.h>

typedef _Float16 f16;
typedef _Float16 f16x8 __attribute__((ext_vector_type(8)));
typedef _Float16 f16x4 __attribute__((ext_vector_type(4)));
typedef float f32x4 __attribute__((ext_vector_type(4)));

#define N_NODES 50000
#define N_EDGES 800000
#define HID 64
#define HEADS 8
#define DH 8
#define LAYERS 6
#define EDGE_DIM 16
#define SIGN_DIM 8
#define NSIGN 3
#define VOC 512
#define NCOMB (VOC * NSIGN)
#define EPS 1e-5f

// coarse-bucket sort params
#define NBUCK 196
#define BUCK_CAP 5120
#define BIN_EPB 4096
#define BIN_EPT 16
#define BIN_NBLK ((N_EDGES + BIN_EPB - 1) / BIN_EPB)

// prep kernel grid ranges
#define WP_BLK 384
#define TE_BLK (LAYERS * (NCOMB / 16))
#define PREP_BLK (WP_BLK + TE_BLK + 1)

__device__ __forceinline__ float dot8(f16x8 a, f16x8 b, float c) {
#if __has_builtin(__builtin_amdgcn_fdot2)
    c = __builtin_amdgcn_fdot2(__builtin_shufflevector(a, a, 0, 1),
                               __builtin_shufflevector(b, b, 0, 1), c, false);
    c = __builtin_amdgcn_fdot2(__builtin_shufflevector(a, a, 2, 3),
                               __builtin_shufflevector(b, b, 2, 3), c, false);
    c = __builtin_amdgcn_fdot2(__builtin_shufflevector(a, a, 4, 5),
                               __builtin_shufflevector(b, b, 4, 5), c, false);
    c = __builtin_amdgcn_fdot2(__builtin_shufflevector(a, a, 6, 7),
                               __builtin_shufflevector(b, b, 6, 7), c, false);
#else
#pragma unroll
    for (int i = 0; i < 8; ++i) c += (float)a[i] * (float)b[i];
#endif
    return c;
}

// ---------------- prep: weight prep + TE table + inits
__global__ __launch_bounds__(256) void k_prep(
    const float* __restrict__ Wq, const float* __restrict__ bq,
    const float* __restrict__ Wk, const float* __restrict__ bk,
    const float* __restrict__ Wv, const float* __restrict__ bv,
    const float* __restrict__ Ws, const float* __restrict__ bs,
    f16* __restrict__ wcatT, float* __restrict__ bcat,
    const float* __restrict__ emb_s, const float* __restrict__ emb_sg,
    const float* __restrict__ We, const float* __restrict__ be,
    const float* __restrict__ Wedge, f16* __restrict__ TE,
    int* __restrict__ bcur, int* __restrict__ rowptr,
    float* __restrict__ gsumR) {
    int b = blockIdx.x;
    int t = threadIdx.x;
    if (b < WP_BLK) {
        int idx = b * 256 + t;
        int l = idx >> 14;
        int r = idx & 16383;
        int c = r >> 6, kk = r & 63;
        int m = c >> 6, cc = c & 63;
        const float* W = (m == 0) ? Wq : (m == 1) ? Wk : (m == 2) ? Wv : Ws;
        wcatT[idx] = (f16)W[l * 4096 + kk * 64 + cc];
        if (kk == 0) {
            const float* B = (m == 0) ? bq : (m == 1) ? bk : (m == 2) ? bv : bs;
            bcat[l * 256 + c] = B[l * 64 + cc];
        }
        return;
    }
    b -= WP_BLK;
    if (b < TE_BLK) {
        __shared__ float T[16][16];
        int l = b / (NCOMB / 16);
        int comb0 = (b % (NCOMB / 16)) * 16;
        int cl = t >> 4, c = t & 15;
        int comb = comb0 + cl;
        int lb = comb / NSIGN, sg = comb % NSIGN;
        float acc = be[c];
        const float* er = emb_s + lb * HID;
#pragma unroll
        for (int j = 0; j < HID; ++j) acc += er[j] * We[j * EDGE_DIM + c];
        const float* sr = emb_sg + sg * SIGN_DIM;
#pragma unroll
        for (int j = 0; j < SIGN_DIM; ++j) acc += sr[j] * We[(HID + j) * EDGE_DIM + c];
        T[cl][c] = acc;
        __syncthreads();
        const float* w = Wedge + l * EDGE_DIM * HID;
#pragma unroll
        for (int rep = 0; rep < 4; ++rep) {
            int idx = rep * 256 + t;
            int cml = idx >> 6, d = idx & 63;
            float a = 0.f;
#pragma unroll
            for (int j = 0; j < EDGE_DIM; ++j) a += T[cml][j] * w[j * HID + d];
            TE[((size_t)l * NCOMB + comb0 + cml) * HID + d] = (f16)a;
        }
        return;
    }
    if (t < NBUCK) bcur[t] = 0;
    for (int i = t; i < 512; i += 256) gsumR[i] = 0.f;
    if (t == 0) rowptr[N_NODES] = N_EDGES;
}

// ---------------- store helper: lane owns 4 consecutive channels of node nn
__device__ __forceinline__ void proj_store(
    f16* __restrict__ q, f16* __restrict__ kv, f16* __restrict__ sk,
    int nn, int cbase, f32x4 z, const float* __restrict__ bcat_l) {
    f16x4 val;
#pragma unroll
    for (int r = 0; r < 4; ++r) val[r] = (f16)(z[r] + bcat_l[cbase + r]);
    int m = cbase >> 6, cc = cbase & 63;
    f16* dst = (m == 0) ? (q + (nn << 6) + cc)
             : (m == 1) ? (kv + (size_t)nn * 128 + cc)
             : (m == 2) ? (kv + (size_t)nn * 128 + 64 + cc)
                        : (sk + (nn << 6) + cc);
    *(f16x4*)dst = val;
}

// ---------------- node features + layer-0 projection (16 nodes/block, A=W B=x)
__global__ __launch_bounds__(256) void k_nfproj(
    const int* __restrict__ xn, const float* __restrict__ emb_s,
    const float* __restrict__ emb_p, const f16* __restrict__ wcatT0,
    const float* __restrict__ bcat0,
    f16* __restrict__ q, f16* __restrict__ kv, f16* __restrict__ sk) {
    __shared__ __align__(16) f16 xs[16][72];
    int t = threadIdx.x;
    int n0 = blockIdx.x * 16;
#pragma unroll
    for (int i = 0; i < 4; ++i) {
        int idx = i * 256 + t;
        int row = idx >> 6, col = idx & 63;
        int n = n0 + row;
        float acc = 0.f;
#pragma unroll
        for (int s = 0; s < 4; ++s) {
            int id = xn[n * 4 + s];
            acc += emb_s[id * HID + col] + emb_p[s * HID + col];
        }
        xs[row][col] = (f16)acc;
    }
    __syncthreads();
    int w = t >> 6, l = t & 63;
    int kb = l >> 4;
    int nn = n0 + (l & 15);
    f16x8 b0 = *(const f16x8*)(&xs[l & 15][kb << 3]);
    f16x8 b1 = *(const f16x8*)(&xs[l & 15][32 + (kb << 3)]);
#pragma unroll
    for (int tt = 0; tt < 4; ++tt) {
        int ct = (w << 2) + tt;
        const f16* wr = wcatT0 + (((ct << 4) + (l & 15)) << 6) + (kb << 3);
        f16x8 a0 = *(const f16x8*)(wr);
        f16x8 a1 = *(const f16x8*)(wr + 32);
        f32x4 z = {0.f, 0.f, 0.f, 0.f};
        z = __builtin_amdgcn_mfma_f32_16x16x32_f16(a0, b0, z, 0, 0, 0);
        z = __builtin_amdgcn_mfma_f32_16x16x32_f16(a1, b1, z, 0, 0, 0);
        proj_store(q, kv, sk, nn, (ct << 4) + ((l >> 4) << 2), z, bcat0);
    }
}

// ---------------- phase 1: bin edges into coarse buckets
__global__ __launch_bounds__(256) void k_bin(
    const int* __restrict__ src, const int* __restrict__ dst,
    const int* __restrict__ label, const int* __restrict__ sign,
    int* __restrict__ bcur, int2* __restrict__ buf) {
    __shared__ int hist[NBUCK];
    __shared__ int base[NBUCK];
    int t = threadIdx.x;
    for (int i = t; i < NBUCK; i += 256) hist[i] = 0;
    __syncthreads();
    int e0 = blockIdx.x * BIN_EPB;
    int pk[BIN_EPT], dl[BIN_EPT], bl[BIN_EPT], loc[BIN_EPT];
#pragma unroll
    for (int i = 0; i < BIN_EPT; ++i) {
        int e = e0 + i * 256 + t;
        bool vld = e < N_EDGES;
        int d = vld ? dst[e] : 0;
        bl[i] = d >> 8;
        dl[i] = d & 255;
        pk[i] = vld ? ((src[e] << 11) | (label[e] * NSIGN + sign[e])) : 0;
        loc[i] = vld ? atomicAdd(&hist[bl[i]], 1) : -1;
    }
    __syncthreads();
    if (t < NBUCK) {
        int h = hist[t];
        int gb = h ? atomicAdd(&bcur[t], h) : 0;
        base[t] = t * BUCK_CAP + gb;
    }
    __syncthreads();
#pragma unroll
    for (int i = 0; i < BIN_EPT; ++i)
        if (loc[i] >= 0) buf[base[bl[i]] + loc[i]] = make_int2(pk[i], dl[i]);
}

// ---------------- phase 2: inline bucket scan + per-bucket rowptr + CSR scatter
__global__ __launch_bounds__(256) void k_place(
    const int* __restrict__ bcur, const int2* __restrict__ buf,
    int* __restrict__ rowptr, int* __restrict__ scomb) {
    __shared__ int hist[256];
    __shared__ int curs[256];
    __shared__ int wsA[4];
    __shared__ int wsB[4];
    __shared__ int sbase;
    int t = threadIdx.x, b = blockIdx.x;
    int lane = t & 63, w = t >> 6;
    int v = (t < NBUCK) ? bcur[t] : 0;
    int incl = v;
#pragma unroll
    for (int o = 1; o < 64; o <<= 1) {
        int u = __shfl_up(incl, o);
        if (lane >= o) incl += u;
    }
    if (lane == 63) wsA[w] = incl;
    hist[t] = 0;
    __syncthreads();
    int woff = 0;
    for (int j = 0; j < w; ++j) woff += wsA[j];
    if (t == b) sbase = woff + incl - v;
    __syncthreads();
    int cnt = bcur[b];
    const int2* bb = buf + (size_t)b * BUCK_CAP;
    for (int i = t; i < cnt; i += 256) atomicAdd(&hist[bb[i].y], 1);
    __syncthreads();
    int hv = hist[t];
    int hincl = hv;
#pragma unroll
    for (int o = 1; o < 64; o <<= 1) {
        int u = __shfl_up(hincl, o);
        if (lane >= o) hincl += u;
    }
    if (lane == 63) wsB[w] = hincl;
    __syncthreads();
    int hoff = 0;
    for (int j = 0; j < w; ++j) hoff += wsB[j];
    int start = sbase + hoff + hincl - hv;
    int n = (b << 8) + t;
    if (n < N_NODES) rowptr[n] = start;
    curs[t] = start;
    __syncthreads();
    for (int i = t; i < cnt; i += 256) {
        int2 r = bb[i];
        int pos = atomicAdd(&curs[r.y], 1);
        scomb[pos] = r.x;
    }
}

// ---------------- MFMA projection (layers 1..5), A=W B=x, coalesced 8B stores
__global__ __launch_bounds__(256) void k_proj(
    const f16* __restrict__ x16, const f16* __restrict__ wcatT_l,
    const float* __restrict__ bcat_l,
    f16* __restrict__ q, f16* __restrict__ kv, f16* __restrict__ sk) {
    int t = threadIdx.x;
    int w = t >> 6, l = t & 63;
    int n0 = blockIdx.x * 16;
    int kb = l >> 4;
    int nn = n0 + (l & 15);
    const f16* xr = x16 + (nn << 6) + (kb << 3);
    f16x8 b0 = *(const f16x8*)(xr);
    f16x8 b1 = *(const f16x8*)(xr + 32);
#pragma unroll
    for (int tt = 0; tt < 4; ++tt) {
        int ct = (w << 2) + tt;
        const f16* wr = wcatT_l + (((ct << 4) + (l & 15)) << 6) + (kb << 3);
        f16x8 a0 = *(const f16x8*)(wr);
        f16x8 a1 = *(const f16x8*)(wr + 32);
        f32x4 z = {0.f, 0.f, 0.f, 0.f};
        z = __builtin_amdgcn_mfma_f32_16x16x32_f16(a0, b0, z, 0, 0, 0);
        z = __builtin_amdgcn_mfma_f32_16x16x32_f16(a1, b1, z, 0, 0, 0);
        proj_store(q, kv, sk, nn, (ct << 4) + ((l >> 4) << 2), z, bcat_l);
    }
}

// ---------------- shared aggregation core: 16 edges/iter, scomb software-pipelined
#define AGG_BODY()                                                               \
    int e = lane >> 3;                                                           \
    int h = lane & 7;                                                            \
    int d = (h << 3) + e;                                                        \
    float skv = (float)sk[(n << 6) + d];                                         \
    f16x8 qf = *(const f16x8*)(q + (n << 6) + (h << 3));                         \
    int rs = rowptr[n], re = rowptr[n + 1];                                      \
    const float scale = 0.35355339059327373f;                                    \
    float lsum = 0.f;                                                            \
    float acc0 = 0.f, acc1 = 0.f, acc2 = 0.f, acc3 = 0.f;                        \
    float acc4 = 0.f, acc5 = 0.f, acc6 = 0.f, acc7 = 0.f;                        \
    bool va = rs + e < re, vb = rs + 8 + e < re;                                 \
    int pa = scomb[va ? rs + e : rs];                                            \
    int pb = scomb[vb ? rs + 8 + e : rs];                                        \
    for (int j0 = rs; j0 < re; j0 += 16) {                                       \
        bool vac = va, vbc = vb;                                                 \
        int pac = pa, pbc = pb;                                                  \
        int jn = j0 + 16;                                                        \
        va = jn + e < re;                                                        \
        vb = jn + 8 + e < re;                                                    \
        pa = scomb[va ? jn + e : rs];                                            \
        pb = scomb[vb ? jn + 8 + e : rs];                                        \
        const f16* kpa = kv + ((size_t)(pac >> 11) << 7) + (h << 3);             \
        const f16* kpb = kv + ((size_t)(pbc >> 11) << 7) + (h << 3);             \
        f16x8 ka = *(const f16x8*)(kpa);                                         \
        f16x8 vaf = *(const f16x8*)(kpa + 64);                                   \
        f16x8 ta = *(const f16x8*)(te + ((pac & 2047) << 6) + (h << 3));         \
        f16x8 kb2 = *(const f16x8*)(kpb);                                        \
        f16x8 vbf = *(const f16x8*)(kpb + 64);                                   \
        f16x8 tb = *(const f16x8*)(te + ((pbc & 2047) << 6) + (h << 3));         \
        float ala = dot8(qf, ka + ta, 0.f) * scale;                              \
        float alb = dot8(qf, kb2 + tb, 0.f) * scale;                             \
        float wa = vac ? __expf(ala) : 0.f;                                      \
        float wb = vbc ? __expf(alb) : 0.f;                                      \
        lsum += wa + wb;                                                         \
        f16x8 vta = vaf + ta;                                                    \
        f16x8 vtb = vbf + tb;                                                    \
        acc0 += wa * (float)vta[0] + wb * (float)vtb[0];                         \
        acc1 += wa * (float)vta[1] + wb * (float)vtb[1];                         \
        acc2 += wa * (float)vta[2] + wb * (float)vtb[2];                         \
        acc3 += wa * (float)vta[3] + wb * (float)vtb[3];                         \
        acc4 += wa * (float)vta[4] + wb * (float)vtb[4];                         \
        acc5 += wa * (float)vta[5] + wb * (float)vtb[5];                         \
        acc6 += wa * (float)vta[6] + wb * (float)vtb[6];                         \
        acc7 += wa * (float)vta[7] + wb * (float)vtb[7];                         \
    }                                                                            \
    _Pragma("unroll")                                                            \
    for (int o = 8; o < 64; o <<= 1) {                                           \
        lsum += __shfl_xor(lsum, o);                                             \
        acc0 += __shfl_xor(acc0, o);                                             \
        acc1 += __shfl_xor(acc1, o);                                             \
        acc2 += __shfl_xor(acc2, o);                                             \
        acc3 += __shfl_xor(acc3, o);                                             \
        acc4 += __shfl_xor(acc4, o);                                             \
        acc5 += __shfl_xor(acc5, o);                                             \
        acc6 += __shfl_xor(acc6, o);                                             \
        acc7 += __shfl_xor(acc7, o);                                             \
    }                                                                            \
    float av = acc0;                                                             \
    av = (e == 1) ? acc1 : av;                                                   \
    av = (e == 2) ? acc2 : av;                                                   \
    av = (e == 3) ? acc3 : av;                                                   \
    av = (e == 4) ? acc4 : av;                                                   \
    av = (e == 5) ? acc5 : av;                                                   \
    av = (e == 6) ? acc6 : av;                                                   \
    av = (e == 7) ? acc7 : av;                                                   \
    float outv = av / (lsum + 1e-16f) + skv;

// ---------------- aggregation + skip + LN/ReLU (layers 0..4)
__global__ __launch_bounds__(256) void k_aggL(
    const f16* __restrict__ q, const f16* __restrict__ kv,
    const f16* __restrict__ sk, const f16* __restrict__ te,
    const int* __restrict__ scomb, const int* __restrict__ rowptr,
    const float* __restrict__ ln_g, const float* __restrict__ ln_b,
    f16* __restrict__ xout) {
    int t = threadIdx.x;
    int wid = t >> 6, lane = t & 63;
    int n = blockIdx.x * 4 + wid;
    AGG_BODY()
    float ssum = outv;
#pragma unroll
    for (int o = 1; o < 64; o <<= 1) ssum += __shfl_xor(ssum, o);
    float mu = ssum * (1.f / 64.f);
    float dv = outv - mu;
    float vs = dv * dv;
#pragma unroll
    for (int o = 1; o < 64; o <<= 1) vs += __shfl_xor(vs, o);
    float var = vs * (1.f / 64.f);
    float yv = ln_g[d] * dv / sqrtf(var + EPS) + ln_b[d];
    xout[(n << 6) + d] = (f16)fmaxf(yv, 0.f);
}

// ---------------- final-layer aggregation + policy head + fused column sums
__global__ __launch_bounds__(256) void k_aggF(
    const f16* __restrict__ q, const f16* __restrict__ kv,
    const f16* __restrict__ sk, const f16* __restrict__ te,
    const int* __restrict__ scomb, const int* __restrict__ rowptr,
    const float* __restrict__ Wp, const float* __restrict__ bp,
    float* __restrict__ pol, float* __restrict__ gsumR) {
    __shared__ float sh[4][64];
    int t = threadIdx.x;
    int wid = t >> 6, lane = t & 63;
    int n = blockIdx.x * 4 + wid;
    AGG_BODY()
    float p0 = outv * Wp[d * 2 + 0];
    float p1 = outv * Wp[d * 2 + 1];
#pragma unroll
    for (int o = 1; o < 64; o <<= 1) {
        p0 += __shfl_xor(p0, o);
        p1 += __shfl_xor(p1, o);
    }
    if (lane == 0) {
        pol[n * 2 + 0] = p0 + bp[0];
        pol[n * 2 + 1] = p1 + bp[1];
    }
    sh[wid][d] = outv;
    __syncthreads();
    if (wid == 0) {
        float s = sh[0][lane] + sh[1][lane] + sh[2][lane] + sh[3][lane];
        atomicAdd(&gsumR[((blockIdx.x & 7) << 6) + lane], s);
    }
}

// ---------------- value head
__global__ __launch_bounds__(64) void k_value(
    const float* __restrict__ gsumR, const float* __restrict__ Wv1,
    const float* __restrict__ bv1, const float* __restrict__ Wv2,
    const float* __restrict__ bv2, float* __restrict__ out) {
    int lane = threadIdx.x;
    __shared__ float g[64];
    float gs = 0.f;
#pragma unroll
    for (int r = 0; r < 8; ++r) gs += gsumR[(r << 6) + lane];
    g[lane] = gs * (1.f / N_NODES);
    __syncthreads();
    float h = bv1[lane];
    for (int i = 0; i < HID; ++i) h += g[i] * Wv1[i * HID + lane];
    h = fmaxf(h, 0.f);
    float p = h * Wv2[lane];
#pragma unroll
    for (int o = 1; o < 64; o <<= 1) p += __shfl_xor(p, o);
    if (lane == 0) out[0] = tanhf(p + bv2[0]);
}

extern "C" void kernel_launch(void* const* d_in, const int* in_sizes, int n_in,
                              void* d_out, int out_size, void* d_ws, size_t ws_size,
                              hipStream_t stream) {
    const int* x_nodes = (const int*)d_in[0];
    const int* edge_index = (const int*)d_in[1];
    const int* edge_label = (const int*)d_in[2];
    const int* edge_sign = (const int*)d_in[3];
    const float* emb_strand = (const float*)d_in[4];
    const float* emb_pos = (const float*)d_in[5];
    const float* emb_sign = (const float*)d_in[6];
    const float* We = (const float*)d_in[7];
    const float* be = (const float*)d_in[8];
    const float* Wq = (const float*)d_in[9];
    const float* bq = (const float*)d_in[10];
    const float* Wk = (const float*)d_in[11];
    const float* bk = (const float*)d_in[12];
    const float* Wv = (const float*)d_in[13];
    const float* bv = (const float*)d_in[14];
    const float* Wedge = (const float*)d_in[15];
    const float* Wskip = (const float*)d_in[16];
    const float* bskip = (const float*)d_in[17];
    const float* ln_g = (const float*)d_in[18];
    const float* ln_b = (const float*)d_in[19];
    const float* Wp = (const float*)d_in[20];
    const float* bp = (const float*)d_in[21];
    const float* Wv1 = (const float*)d_in[22];
    const float* bv1 = (const float*)d_in[23];
    const float* Wv2 = (const float*)d_in[24];
    const float* bv2 = (const float*)d_in[25];
    float* out = (float*)d_out;

    const int* src = edge_index;
    const int* dst = edge_index + N_EDGES;

    char* ws = (char*)d_ws;
    size_t off = 0;
    auto alloc = [&](size_t bytes) -> void* {
        void* p = ws + off;
        off += (bytes + 255) & ~(size_t)255;
        return p;
    };
    f16* x16 = (f16*)alloc((size_t)N_NODES * HID * 2);
    f16* q = (f16*)alloc((size_t)N_NODES * HID * 2);
    f16* kv = (f16*)alloc((size_t)N_NODES * 128 * 2);
    f16* sk = (f16*)alloc((size_t)N_NODES * HID * 2);
    int* scomb = (int*)alloc((size_t)N_EDGES * 4);
    int2* binbuf = (int2*)alloc((size_t)NBUCK * BUCK_CAP * 8);
    int* rowptr = (int*)alloc((size_t)(N_NODES + 1) * 4);
    int* bcur = (int*)alloc((size_t)NBUCK * 4);
    f16* TE = (f16*)alloc((size_t)LAYERS * NCOMB * HID * 2);
    f16* wcatT = (f16*)alloc((size_t)LAYERS * 256 * HID * 2);
    float* bcat = (float*)alloc((size_t)LAYERS * 256 * 4);
    float* gsumR = (float*)alloc(512 * 4);

    k_prep<<<PREP_BLK, 256, 0, stream>>>(
        Wq, bq, Wk, bk, Wv, bv, Wskip, bskip, wcatT, bcat,
        emb_strand, emb_sign, We, be, Wedge, TE, bcur, rowptr, gsumR);
    k_nfproj<<<N_NODES / 16, 256, 0, stream>>>(
        x_nodes, emb_strand, emb_pos, wcatT, bcat, q, kv, sk);
    k_bin<<<BIN_NBLK, 256, 0, stream>>>(src, dst, edge_label, edge_sign, bcur, binbuf);
    k_place<<<NBUCK, 256, 0, stream>>>(bcur, binbuf, rowptr, scomb);

    for (int l = 0; l < LAYERS - 1; ++l) {
        k_aggL<<<N_NODES / 4, 256, 0, stream>>>(
            q, kv, sk, TE + (size_t)l * NCOMB * HID, scomb, rowptr,
            ln_g + (size_t)l * HID, ln_b + (size_t)l * HID, x16);
        k_proj<<<N_NODES / 16, 256, 0, stream>>>(
            x16, wcatT + (size_t)(l + 1) * 256 * HID, bcat + (size_t)(l + 1) * 256,
            q, kv, sk);
    }
    k_aggF<<<N_NODES / 4, 256, 0, stream>>>(
        q, kv, sk, TE + (size_t)(LAYERS - 1) * NCOMB * HID, scomb, rowptr,
        Wp, bp, out, gsumR);
    k_value<<<1, 64, 0, stream>>>(gsumR, Wv1, bv1, Wv2, bv2, out + 2 * N_NODES);
}